// Round 1
// 300.649 us; speedup vs baseline: 1.3025x; 1.3025x over previous
//
#include <hip/hip_runtime.h>

#define BATCH 8
#define HH 256
#define WW 256
#define CI 64
#define CO 64
#define STYLE_IN 512

typedef __bf16 bf16x8 __attribute__((ext_vector_type(8)));
typedef float  f32x4  __attribute__((ext_vector_type(4)));
typedef unsigned short u16x8 __attribute__((ext_vector_type(8)));

// round-to-nearest-even fp32 -> bf16
static __device__ inline unsigned short f2bf(float f) {
    union { float f; unsigned int u; } a; a.f = f;
    unsigned int u = a.u;
    u += 0x7fffu + ((u >> 16) & 1u);
    return (unsigned short)(u >> 16);
}

// ---------------------------------------------------------------------------
// Kernel 1: EqualLinear modulation + demodulation -> bf16 weights
// Output layout: wbf[b][tap][co][ci], tap = kh*3+kw, ci contiguous.
// ---------------------------------------------------------------------------
__global__ __launch_bounds__(256) void modulate_kernel(
    const float* __restrict__ style, const float* __restrict__ mod_weight,
    const float* __restrict__ mod_bias, const float* __restrict__ weight,
    unsigned short* __restrict__ wbf)
{
    const int b = blockIdx.x;
    const int t = threadIdx.x;
    __shared__ float sp[4][64];
    __shared__ float s_mod[64];
    __shared__ float dpart[64][4];
    __shared__ float demod[64];

    const float LIN_SCALE  = 0.044194173824159216f;  // 1/sqrt(512)
    const float CONV_SCALE = 0.041666666666666664f;  // 1/sqrt(64*9)

    {
        const int ci = t & 63, part = t >> 6;   // 4 partials per ci
        float acc = 0.f;
        const float* st = style + b * STYLE_IN + part * 128;
        const float* mw = mod_weight + part * 128 * 64 + ci;
        #pragma unroll 8
        for (int j = 0; j < 128; ++j) acc += st[j] * mw[j * 64];
        sp[part][ci] = acc;
    }
    __syncthreads();
    if (t < 64)
        s_mod[t] = (sp[0][t] + sp[1][t] + sp[2][t] + sp[3][t]) * LIN_SCALE + mod_bias[t];
    __syncthreads();

    {
        const int co = t >> 2, part = t & 3;    // 4 partials x (16 ci x 9 taps)
        float acc = 0.f;
        const float* wp = weight + co * 576 + part * 144;
        #pragma unroll
        for (int ci2 = 0; ci2 < 16; ++ci2) {
            float s = s_mod[part * 16 + ci2];
            #pragma unroll
            for (int tp = 0; tp < 9; ++tp) {
                float v = wp[ci2 * 9 + tp] * s;
                acc += v * v;
            }
        }
        dpart[co][part] = acc * (CONV_SCALE * CONV_SCALE);
    }
    __syncthreads();
    if (t < 64)
        demod[t] = rsqrtf(dpart[t][0] + dpart[t][1] + dpart[t][2] + dpart[t][3] + 1e-8f);
    __syncthreads();

    for (int i = t; i < 9 * 64 * 64; i += 256) {
        int ci  = i & 63;
        int co  = (i >> 6) & 63;
        int tap = i >> 12;
        float v = CONV_SCALE * weight[co * 576 + ci * 9 + tap] * s_mod[ci] * demod[co];
        wbf[((b * 9 + tap) * 64 + co) * 64 + ci] = f2bf(v);
    }
}

// ---------------------------------------------------------------------------
// Kernel 2: implicit-GEMM conv, strip-mined y, 4-row LDS ring.
//
// Decomposition change vs previous version: wave = 64 px x 32 co (mi=4, ni=2)
// instead of 32 px x 64 co. A wave now needs only 9*2*2 = 36 weight
// fragments (144 VGPRs) -> loaded ONCE into registers before the j-loop.
// This removes the 72 per-lane global weight loads per iteration that sat
// at L2 latency on the MFMA dependency chain (the measured latency-bound
// stall: 7.8% MfmaUtil / 16% HBM / 22% occupancy).
//
// vbuf double-buffer dropped to single buffer: issue() already runs after
// __syncthreads (which drains lgkmcnt(0)), so the WAR hazard on vbuf is
// ordered by the existing barrier anyway. Saves 40 VGPRs so wreg fits at
// 2 waves/SIMD without spill.
// ---------------------------------------------------------------------------
#define PXS 72                      // pixel stride in bf16 elems (64 + 8 pad)
#define ROWPX 130                   // 128 + 2 halo
#define ROW_ELEMS (ROWPX * PXS)     // 9360 shorts = 18,720 B per row

__global__ __launch_bounds__(256, 2) void conv_kernel(
    const float* __restrict__ x, const unsigned short* __restrict__ wbf,
    float* __restrict__ out)
{
    __shared__ unsigned short xs[4 * ROW_ELEMS];   // 74,880 B -> 2 blocks/CU

    const int tid = threadIdx.x;
    const int x0  = blockIdx.x * 128;
    const int y0  = blockIdx.y * 8;       // multiple of 8 -> slot math uses &3
    const int b   = blockIdx.z;

    // --- staging: 1040 items/row (px 0..129 x 8-ch groups of 8 floats) ---
    auto issue = [&](int yin, f32x4* v) {
        const bool rok = (unsigned)yin < (unsigned)HH;
        const float* src = x + ((size_t)(b * HH + (rok ? yin : 0))) * WW * CI;
        #pragma unroll
        for (int k = 0; k < 5; ++k) {
            int i  = tid + k * 256;
            int px = i >> 3, cg = i & 7;
            int xin = x0 - 1 + px;
            bool ok = rok && ((unsigned)xin < (unsigned)WW) && (i < 1040);
            const float* p = src + (size_t)xin * CI + cg * 8;
            f32x4 z = {0.f, 0.f, 0.f, 0.f};
            v[2 * k]     = ok ? *(const f32x4*)p       : z;
            v[2 * k + 1] = ok ? *(const f32x4*)(p + 4) : z;
        }
    };
    auto commit = [&](int slot, const f32x4* v) {
        unsigned short* dst = xs + slot * ROW_ELEMS;
        #pragma unroll
        for (int k = 0; k < 5; ++k) {
            int i = tid + k * 256;
            if (k == 4 && i >= 1040) continue;
            int px = i >> 3, cg = i & 7;
            u16x8 u;
            #pragma unroll
            for (int e = 0; e < 4; ++e) {
                u[e]     = f2bf(v[2 * k][e]);
                u[e + 4] = f2bf(v[2 * k + 1][e]);
            }
            *(u16x8*)&dst[px * PXS + cg * 8] = u;
        }
    };

    // prologue: rows y0-1, y0, y0+1 -> slots 0,1,2
    {
        f32x4 v[10];
        issue(y0 - 1, v); commit(0, v);
        issue(y0,     v); commit(1, v);
        issue(y0 + 1, v); commit(2, v);
    }

    const int wave = tid >> 6, lane = tid & 63;
    const int lm = lane & 15, lq = lane >> 4;
    const int wr = wave >> 1;             // pixel half: px base = wr*64
    const int wc = wave & 1;              // co half:    co base = wc*32
    const int p0 = wr * 64;

    // Load this wave's 36 weight fragments into registers (loop-invariant).
    // wreg[tap][ni][ks]: co = wc*32 + ni*16 + lm, ci = ks*32 + lq*8 .. +7
    bf16x8 wreg[9][2][2];
    {
        const unsigned short* wl = wbf + (size_t)b * 9 * 4096
                                 + (size_t)(wc * 32 + lm) * 64 + lq * 8;
        #pragma unroll
        for (int tap = 0; tap < 9; ++tap)
            #pragma unroll
            for (int ni = 0; ni < 2; ++ni)
                #pragma unroll
                for (int ks = 0; ks < 2; ++ks)
                    wreg[tap][ni][ks] =
                        *(const bf16x8*)(wl + tap * 4096 + ni * 1024 + ks * 32);
    }

    __syncthreads();

    const int aoff_lane = (p0 + lm) * PXS + lq * 8;

    f32x4 vbuf[10];
    issue(y0 + 2, vbuf);          // in flight over first MFMA phase

    #pragma unroll
    for (int j = 0; j < 8; ++j) {
        const int y = y0 + j;

        f32x4 acc[4][2];
        #pragma unroll
        for (int mi = 0; mi < 4; ++mi)
            #pragma unroll
            for (int ni = 0; ni < 2; ++ni)
                acc[mi][ni] = (f32x4){0.f, 0.f, 0.f, 0.f};

        const unsigned short* bases[3] = {
            xs + ((y)     & 3) * ROW_ELEMS,
            xs + ((y + 1) & 3) * ROW_ELEMS,
            xs + ((y + 2) & 3) * ROW_ELEMS,
        };

        #pragma unroll
        for (int kh = 0; kh < 3; ++kh) {
            const unsigned short* bs = bases[kh] + aoff_lane;
            #pragma unroll
            for (int kw = 0; kw < 3; ++kw) {
                #pragma unroll
                for (int ks = 0; ks < 2; ++ks) {
                    #pragma unroll
                    for (int mi = 0; mi < 4; ++mi) {
                        // B operand: pixels, n = px = p0 + mi*16 + lm
                        bf16x8 xf = *(const bf16x8*)(bs + (mi * 16 + kw) * PXS + ks * 32);
                        // A operand: weights from registers
                        acc[mi][0] = __builtin_amdgcn_mfma_f32_16x16x32_bf16(
                            wreg[kh * 3 + kw][0][ks], xf, acc[mi][0], 0, 0, 0);
                        acc[mi][1] = __builtin_amdgcn_mfma_f32_16x16x32_bf16(
                            wreg[kh * 3 + kw][1][ks], xf, acc[mi][1], 0, 0, 0);
                    }
                }
            }
        }

        // write row y+2 (prefetched last iter) into slot (y+3)&3
        commit((y + 3) & 3, vbuf);

        __syncthreads();   // drains ds_writes; barrier orders vbuf reuse

        // issue next row's loads immediately (in flight over epilogue + MFMA)
        if (j < 7) issue(y + 3, vbuf);

        // epilogue: D col = lane&15 = px-in-group, row = lq*4+reg = co-in-group
        float* op = out + ((size_t)(b * HH + y) * WW + x0) * CO;
        #pragma unroll
        for (int mi = 0; mi < 4; ++mi) {
            int pix = p0 + mi * 16 + lm;
            #pragma unroll
            for (int ni = 0; ni < 2; ++ni)
                __builtin_nontemporal_store(acc[mi][ni],
                    (f32x4*)(op + (size_t)pix * CO + wc * 32 + ni * 16 + lq * 4));
        }
    }
}

// ---------------------------------------------------------------------------
extern "C" void kernel_launch(void* const* d_in, const int* in_sizes, int n_in,
                              void* d_out, int out_size, void* d_ws, size_t ws_size,
                              hipStream_t stream) {
    const float* inputs     = (const float*)d_in[0];   // [8,256,256,64]
    const float* style      = (const float*)d_in[1];   // [8,512]
    const float* mod_weight = (const float*)d_in[2];   // [512,64]
    const float* mod_bias   = (const float*)d_in[3];   // [64]
    const float* weight     = (const float*)d_in[4];   // [1,64,64,3,3]
    float* out = (float*)d_out;
    unsigned short* wbf = (unsigned short*)d_ws;       // [8][9][64][64] bf16

    modulate_kernel<<<BATCH, 256, 0, stream>>>(style, mod_weight, mod_bias, weight, wbf);
    conv_kernel<<<dim3(2, 32, BATCH), 256, 0, stream>>>(inputs, wbf, out);
}

// Round 2
// 277.679 us; speedup vs baseline: 1.4103x; 1.0827x over previous
//
#include <hip/hip_runtime.h>

#define BATCH 8
#define HH 256
#define WW 256
#define CI 64
#define CO 64
#define STYLE_IN 512

typedef __bf16 bf16x8 __attribute__((ext_vector_type(8)));
typedef float  f32x4  __attribute__((ext_vector_type(4)));
typedef unsigned short u16x8 __attribute__((ext_vector_type(8)));

// round-to-nearest-even fp32 -> bf16
static __device__ inline unsigned short f2bf(float f) {
    union { float f; unsigned int u; } a; a.f = f;
    unsigned int u = a.u;
    u += 0x7fffu + ((u >> 16) & 1u);
    return (unsigned short)(u >> 16);
}

static __device__ inline bf16x8 as_bf(u16x8 v) {
    union { u16x8 u; bf16x8 b; } c; c.u = v; return c.b;
}

// ---------------------------------------------------------------------------
// Kernel 1: EqualLinear modulation + demodulation -> bf16 weights
// Output layout: wbf[b][tap][co][ci], tap = kh*3+kw, ci contiguous.
// Parallelized: grid (BATCH, 8); blockIdx.y = co octet. Each block recomputes
// s_mod (cheap, 32k MACs) and handles demod + write for its 8 co.
// ---------------------------------------------------------------------------
__global__ __launch_bounds__(256) void modulate_kernel(
    const float* __restrict__ style, const float* __restrict__ mod_weight,
    const float* __restrict__ mod_bias, const float* __restrict__ weight,
    unsigned short* __restrict__ wbf)
{
    const int b   = blockIdx.x;
    const int oct = blockIdx.y;          // co in [oct*8, oct*8+8)
    const int t   = threadIdx.x;
    __shared__ float sp[4][64];
    __shared__ float s_mod[64];
    __shared__ float dpart[8][32];
    __shared__ float demod[8];

    const float LIN_SCALE  = 0.044194173824159216f;  // 1/sqrt(512)
    const float CONV_SCALE = 0.041666666666666664f;  // 1/sqrt(64*9)

    {
        const int ci = t & 63, part = t >> 6;   // 4 partials per ci
        float acc = 0.f;
        const float* st = style + b * STYLE_IN + part * 128;
        const float* mw = mod_weight + part * 128 * 64 + ci;
        #pragma unroll 8
        for (int j = 0; j < 128; ++j) acc += st[j] * mw[j * 64];
        sp[part][ci] = acc;
    }
    __syncthreads();
    if (t < 64)
        s_mod[t] = (sp[0][t] + sp[1][t] + sp[2][t] + sp[3][t]) * LIN_SCALE + mod_bias[t];
    __syncthreads();

    {
        // demod partials: 8 co x 32 partials, each partial = 2 ci x 9 taps
        const int col = t >> 5, part = t & 31;
        float acc = 0.f;
        const float* wp = weight + (oct * 8 + col) * 576 + part * 18;
        #pragma unroll
        for (int ci2 = 0; ci2 < 2; ++ci2) {
            float s = s_mod[part * 2 + ci2];
            #pragma unroll
            for (int tp = 0; tp < 9; ++tp) {
                float v = wp[ci2 * 9 + tp] * s;
                acc += v * v;
            }
        }
        dpart[col][part] = acc * (CONV_SCALE * CONV_SCALE);
    }
    __syncthreads();
    if (t < 8) {
        float s = 0.f;
        #pragma unroll
        for (int p = 0; p < 32; ++p) s += dpart[t][p];
        demod[t] = rsqrtf(s + 1e-8f);
    }
    __syncthreads();

    // write 8 co x 9 taps x 64 ci = 4608 elems; ci contiguous -> coalesced
    for (int i = t; i < 4608; i += 256) {
        int ci  = i & 63;
        int col = (i >> 6) & 7;
        int tap = i >> 9;
        float v = CONV_SCALE * weight[(oct * 8 + col) * 576 + ci * 9 + tap]
                * s_mod[ci] * demod[col];
        wbf[((b * 9 + tap) * 64 + oct * 8 + col) * 64 + ci] = f2bf(v);
    }
}

// ---------------------------------------------------------------------------
// Kernel 2: implicit-GEMM conv, strip-mined y, 4-row LDS ring.
// wave = 64 px x 32 co (mi=4, ni=2): 36 weight fragments (144 VGPRs).
//
// This round: weights are FORCED register-resident. Round-1 counters showed
// VGPR_Count=128 (< the 144 wreg needs) -> with the j-loop fully unrolled and
// wbf __restrict__, the allocator legally re-loaded the fragments every
// iteration, keeping L2 latency on the MFMA chain. Fix:
//   (a) j-loop rolled (#pragma unroll 1) so the 36 loads are LICM'd with a
//       loop-spanning live range;
//   (b) empty asm "+v" pins make the values opaque -> re-load from global is
//       illegal, allocator must keep them (or spill to scratch, visible in
//       the resource report).
// ---------------------------------------------------------------------------
#define PXS 72                      // pixel stride in bf16 elems (64 + 8 pad)
#define ROWPX 130                   // 128 + 2 halo
#define ROW_ELEMS (ROWPX * PXS)     // 9360 shorts = 18,720 B per row

__global__ __launch_bounds__(256, 2) void conv_kernel(
    const float* __restrict__ x, const unsigned short* __restrict__ wbf,
    float* __restrict__ out)
{
    __shared__ unsigned short xs[4 * ROW_ELEMS];   // 74,880 B -> 2 blocks/CU

    const int tid = threadIdx.x;
    const int x0  = blockIdx.x * 128;
    const int y0  = blockIdx.y * 8;       // multiple of 8 -> slot math uses &3
    const int b   = blockIdx.z;

    // --- staging: 1040 items/row (px 0..129 x 8-ch groups of 8 floats) ---
    auto issue = [&](int yin, f32x4* v) {
        const bool rok = (unsigned)yin < (unsigned)HH;
        const float* src = x + ((size_t)(b * HH + (rok ? yin : 0))) * WW * CI;
        #pragma unroll
        for (int k = 0; k < 5; ++k) {
            int i  = tid + k * 256;
            int px = i >> 3, cg = i & 7;
            int xin = x0 - 1 + px;
            bool ok = rok && ((unsigned)xin < (unsigned)WW) && (i < 1040);
            const float* p = src + (size_t)xin * CI + cg * 8;
            f32x4 z = {0.f, 0.f, 0.f, 0.f};
            v[2 * k]     = ok ? *(const f32x4*)p       : z;
            v[2 * k + 1] = ok ? *(const f32x4*)(p + 4) : z;
        }
    };
    auto commit = [&](int slot, const f32x4* v) {
        unsigned short* dst = xs + slot * ROW_ELEMS;
        #pragma unroll
        for (int k = 0; k < 5; ++k) {
            int i = tid + k * 256;
            if (k == 4 && i >= 1040) continue;
            int px = i >> 3, cg = i & 7;
            u16x8 u;
            #pragma unroll
            for (int e = 0; e < 4; ++e) {
                u[e]     = f2bf(v[2 * k][e]);
                u[e + 4] = f2bf(v[2 * k + 1][e]);
            }
            *(u16x8*)&dst[px * PXS + cg * 8] = u;
        }
    };

    // prologue: rows y0-1, y0, y0+1 -> slots 0,1,2
    {
        f32x4 v[10];
        issue(y0 - 1, v); commit(0, v);
        issue(y0,     v); commit(1, v);
        issue(y0 + 1, v); commit(2, v);
    }

    const int wave = tid >> 6, lane = tid & 63;
    const int lm = lane & 15, lq = lane >> 4;
    const int wr = wave >> 1;             // pixel half: px base = wr*64
    const int wc = wave & 1;              // co half:    co base = wc*32
    const int p0 = wr * 64;

    // Load this wave's 36 weight fragments into registers (loop-invariant).
    // wreg[tap][ni][ks]: co = wc*32 + ni*16 + lm, ci = ks*32 + lq*8 .. +7
    u16x8 wreg[9][2][2];
    {
        const unsigned short* wl = wbf + (size_t)b * 9 * 4096
                                 + (size_t)(wc * 32 + lm) * 64 + lq * 8;
        #pragma unroll
        for (int tap = 0; tap < 9; ++tap)
            #pragma unroll
            for (int ni = 0; ni < 2; ++ni)
                #pragma unroll
                for (int ks = 0; ks < 2; ++ks)
                    wreg[tap][ni][ks] =
                        *(const u16x8*)(wl + tap * 4096 + ni * 1024 + ks * 32);
    }
    // Pin: values become opaque -> compiler cannot re-load them from global
    // inside the loop; they must stay in the (unified VGPR/AGPR) file.
    #pragma unroll
    for (int tap = 0; tap < 9; ++tap)
        #pragma unroll
        for (int ni = 0; ni < 2; ++ni)
            #pragma unroll
            for (int ks = 0; ks < 2; ++ks)
                asm volatile("" : "+v"(wreg[tap][ni][ks]));

    __syncthreads();

    const int aoff_lane = (p0 + lm) * PXS + lq * 8;

    f32x4 vbuf[10];
    issue(y0 + 2, vbuf);          // in flight over first MFMA phase

    #pragma unroll 1
    for (int j = 0; j < 8; ++j) {
        const int y = y0 + j;

        f32x4 acc[4][2];
        #pragma unroll
        for (int mi = 0; mi < 4; ++mi)
            #pragma unroll
            for (int ni = 0; ni < 2; ++ni)
                acc[mi][ni] = (f32x4){0.f, 0.f, 0.f, 0.f};

        const unsigned short* bases[3] = {
            xs + ((y)     & 3) * ROW_ELEMS,
            xs + ((y + 1) & 3) * ROW_ELEMS,
            xs + ((y + 2) & 3) * ROW_ELEMS,
        };

        #pragma unroll
        for (int kh = 0; kh < 3; ++kh) {
            const unsigned short* bs = bases[kh] + aoff_lane;
            #pragma unroll
            for (int kw = 0; kw < 3; ++kw) {
                #pragma unroll
                for (int ks = 0; ks < 2; ++ks) {
                    #pragma unroll
                    for (int mi = 0; mi < 4; ++mi) {
                        // B operand: pixels, n = px = p0 + mi*16 + lm
                        bf16x8 xf = *(const bf16x8*)(bs + (mi * 16 + kw) * PXS + ks * 32);
                        // A operand: weights from registers
                        acc[mi][0] = __builtin_amdgcn_mfma_f32_16x16x32_bf16(
                            as_bf(wreg[kh * 3 + kw][0][ks]), xf, acc[mi][0], 0, 0, 0);
                        acc[mi][1] = __builtin_amdgcn_mfma_f32_16x16x32_bf16(
                            as_bf(wreg[kh * 3 + kw][1][ks]), xf, acc[mi][1], 0, 0, 0);
                    }
                }
            }
        }

        // write row y+2 (prefetched last iter) into slot (y+3)&3
        commit((y + 3) & 3, vbuf);

        __syncthreads();   // drains ds_writes; barrier orders vbuf reuse

        // issue next row's loads immediately (in flight over epilogue + MFMA)
        if (j < 7) issue(y + 3, vbuf);

        // epilogue: D col = lane&15 = px-in-group, row = lq*4+reg = co-in-group
        float* op = out + ((size_t)(b * HH + y) * WW + x0) * CO;
        #pragma unroll
        for (int mi = 0; mi < 4; ++mi) {
            int pix = p0 + mi * 16 + lm;
            #pragma unroll
            for (int ni = 0; ni < 2; ++ni)
                __builtin_nontemporal_store(acc[mi][ni],
                    (f32x4*)(op + (size_t)pix * CO + wc * 32 + ni * 16 + lq * 4));
        }
    }
}

// ---------------------------------------------------------------------------
extern "C" void kernel_launch(void* const* d_in, const int* in_sizes, int n_in,
                              void* d_out, int out_size, void* d_ws, size_t ws_size,
                              hipStream_t stream) {
    const float* inputs     = (const float*)d_in[0];   // [8,256,256,64]
    const float* style      = (const float*)d_in[1];   // [8,512]
    const float* mod_weight = (const float*)d_in[2];   // [512,64]
    const float* mod_bias   = (const float*)d_in[3];   // [64]
    const float* weight     = (const float*)d_in[4];   // [1,64,64,3,3]
    float* out = (float*)d_out;
    unsigned short* wbf = (unsigned short*)d_ws;       // [8][9][64][64] bf16

    modulate_kernel<<<dim3(BATCH, 8), 256, 0, stream>>>(style, mod_weight, mod_bias, weight, wbf);
    conv_kernel<<<dim3(2, 32, BATCH), 256, 0, stream>>>(inputs, wbf, out);
}